// Round 9
// baseline (92.930 us; speedup 1.0000x reference)
//
#include <hip/hip_runtime.h>
#include <math.h>

#define BB 16
#define NN 256
#define DD 32
#define RG 8               // rows per block
#define BPB (NN / RG)      // blocks per batch = 32

// Two-pass recompute scheme — m never touches memory:
//   pass<false> (K1): compute m per (row,col), reduce -> rowsum/rowsq only
//                     (32 KB total written).
//   pass<true>  (K2): redundant per-block batch stats from rowsum/rowsq
//                     (2 KB, L2-hot), recompute m identically, write
//                     normalized output directly (4 MB, the only big store).
// Saves the 4 MB m write + 4 MB re-read and one kernel launch vs round 7/8.
//
// Body = round-7's verified K_pair: stage x[b] (32 KB LDS, float4-granule
// XOR swizzle), per-thread redundant u = x_t @ W_top (4 passes x 8 acc),
// per-block v rows, pair compute, deterministic shuffle trees.
// LayerNorm algebra: with m2[i,j] = m[i,j] + rowmean_i,
//   sum(m2) = 2*sum(m);  sum(m2^2) = sum(m^2) + 3*N*sum_i(rowmean_i^2)
template<bool FINAL>
__attribute__((amdgpu_flat_work_group_size(256, 256), amdgpu_waves_per_eu(2, 2)))
__global__ void pass_kernel(
    const float* __restrict__ x,
    const float* __restrict__ W_out, const float* __restrict__ b_out,
    const float* __restrict__ W_cat, const float* __restrict__ b_cat,
    const float* __restrict__ W_f1,  const float* __restrict__ b_f1,
    const float* __restrict__ W_f2,  const float* __restrict__ b_f2,
    float* __restrict__ rowsum, float* __restrict__ rowsq,
    float* __restrict__ out)
{
    __shared__ float4 lx4[NN * 8];              // 32KB swizzled x[b]
    __shared__ float4 lv4[RG * 8];              // 512B rows' v
    __shared__ float  red0[RG][4], red1[RG][4];
    __shared__ float  sred[12], stat[2];

    const int t  = threadIdx.x;                 // column j
    const int b  = blockIdx.x >> 5;
    const int i0 = (blockIdx.x & 31) * RG;

    // ---- stage x[b], swizzled ----
    const float4* xb4 = (const float4*)(x + (size_t)b * NN * DD);
#pragma unroll
    for (int k = 0; k < 8; ++k) {
        int f = k * 256 + t;                    // 2048 float4s
        int n = f >> 3, c = f & 7;
        lx4[n * 8 + (c ^ (n & 7))] = xb4[f];
    }
    __syncthreads();

    // ---- my column x_t -> regs ----
    float xj[DD];
#pragma unroll
    for (int c = 0; c < 8; ++c) {
        float4 xx = lx4[t * 8 + (c ^ (t & 7))];
        xj[4*c+0] = xx.x; xj[4*c+1] = xx.y; xj[4*c+2] = xx.z; xj[4*c+3] = xx.w;
    }

    // ---- u_t = x_t @ W_top, 4 passes x 8 accumulators (uniform s_loads) ----
    float u[DD];
#pragma unroll
    for (int p = 0; p < 4; ++p) {
        float acc[8];
#pragma unroll
        for (int j8 = 0; j8 < 8; ++j8) acc[j8] = 0.f;
#pragma unroll
        for (int k = 0; k < DD; ++k) {
            float xv = xj[k];
#pragma unroll
            for (int j8 = 0; j8 < 8; ++j8)
                acc[j8] += xv * W_out[k * DD + p * 8 + j8];
        }
#pragma unroll
        for (int j8 = 0; j8 < 8; ++j8) u[p * 8 + j8] = acc[j8];
    }

    // ---- v for my block's 8 rows (thread = (row, dim)) ----
    {
        int r = t >> 5, d = t & 31;
        int i = i0 + r;
        const float* lxf = (const float*)lx4;
        float sv = 0.f;
#pragma unroll
        for (int k = 0; k < DD; ++k) {
            float xv = lxf[(i * 8 + ((k >> 2) ^ (i & 7))) * 4 + (k & 3)];
            sv += xv * W_out[(k + DD) * DD + d];
        }
        ((float*)lv4)[r * DD + d] = sv + b_out[d];
    }

    // small weights (wave-uniform -> scalar regs)
    float wcv[DD];
#pragma unroll
    for (int d = 0; d < DD; ++d) wcv[d] = W_cat[d];
    float f1a[8], f1b[8], fb1[8], f2w[8];
#pragma unroll
    for (int k = 0; k < 8; ++k) {
        f1a[k] = W_f1[k];        // W_f1[0,k]
        f1b[k] = W_f1[8 + k];    // W_f1[1,k]
        fb1[k] = b_f1[k];
        f2w[k] = W_f2[k];
    }
    const float bcat = b_cat[0], bf2 = b_f2[0];
    const int lane = t & 63, wv = t >> 6;

    __syncthreads();                            // lv4 ready

    // ---- FINAL: batch stats from K1's row-partials (redundant/block) ----
    float mu = 0.f, rstd = 0.f;
    if constexpr (FINAL) {
        float rs = rowsum[b * NN + t];
        float rq = rowsq [b * NN + t];
        float rr = rs * (1.f / NN);
        float sM = rs, sQ = rq, sR = rr * rr;
#pragma unroll
        for (int off = 32; off; off >>= 1) {
            sM += __shfl_down(sM, off);
            sQ += __shfl_down(sQ, off);
            sR += __shfl_down(sR, off);
        }
        if (lane == 0) { sred[wv] = sM; sred[4 + wv] = sQ; sred[8 + wv] = sR; }
        __syncthreads();
        if (t == 0) {
            float sumM  = sred[0] + sred[1] + sred[2] + sred[3];
            float sumQ  = sred[4] + sred[5] + sred[6] + sred[7];
            float sumR2 = sred[8] + sred[9] + sred[10] + sred[11];
            const float inv = 1.f / ((float)NN * (float)NN);
            float m_  = 2.f * sumM * inv;
            float ex2 = (sumQ + 3.f * (float)NN * sumR2) * inv;
            stat[0] = m_;
            stat[1] = rsqrtf(ex2 - m_ * m_ + 1e-5f);
        }
        __syncthreads();
        mu = stat[0]; rstd = stat[1];
    }

    // ---- pair loop ----
#pragma unroll
    for (int r = 0; r < RG; ++r) {
        const int i = i0 + r;
        float e = 0.f, mp = 0.f;
#pragma unroll
        for (int q = 0; q < 8; ++q) {
            float4 vi = lv4[r * 8 + q];               // broadcast
            float4 xi = lx4[i * 8 + (q ^ (i & 7))];   // broadcast
            e += fmaxf(u[4*q+0] + vi.x, 0.f) * wcv[4*q+0];
            e += fmaxf(u[4*q+1] + vi.y, 0.f) * wcv[4*q+1];
            e += fmaxf(u[4*q+2] + vi.z, 0.f) * wcv[4*q+2];
            e += fmaxf(u[4*q+3] + vi.w, 0.f) * wcv[4*q+3];
            mp += xj[4*q+0]*xi.x + xj[4*q+1]*xi.y + xj[4*q+2]*xi.z + xj[4*q+3]*xi.w;
        }
        e = fmaxf(e + bcat, 0.f);
        float mlin = (t == i) ? 0.f : e;
        float s = bf2;
#pragma unroll
        for (int k = 0; k < 8; ++k)
            s += fmaxf(mlin * f1a[k] + mp * f1b[k] + fb1[k], 0.f) * f2w[k];
        float w = 1.f / (1.f + __expf(-s));
        float m = w * mlin + (1.f - w) * mp;

        if constexpr (FINAL) {
            float ri = rowsum[b * NN + i] * (1.f / NN);   // uniform, L1-hot
            out[((size_t)b * NN + i) * NN + t] = (m + ri - mu) * rstd;
        } else {
            float sm = m, sq = m * m;                 // deterministic tree
#pragma unroll
            for (int off = 32; off; off >>= 1) {
                sm += __shfl_down(sm, off);
                sq += __shfl_down(sq, off);
            }
            if (lane == 0) { red0[r][wv] = sm; red1[r][wv] = sq; }
        }
    }

    if constexpr (!FINAL) {
        __syncthreads();
        if (t < RG) {
            rowsum[b * NN + i0 + t] = red0[t][0] + red0[t][1] + red0[t][2] + red0[t][3];
            rowsq [b * NN + i0 + t] = red1[t][0] + red1[t][1] + red1[t][2] + red1[t][3];
        }
    }
}

extern "C" void kernel_launch(void* const* d_in, const int* in_sizes, int n_in,
                              void* d_out, int out_size, void* d_ws, size_t ws_size,
                              hipStream_t stream)
{
    const float* x     = (const float*)d_in[0];
    const float* W_out = (const float*)d_in[1];
    const float* b_out = (const float*)d_in[2];
    const float* W_cat = (const float*)d_in[3];
    const float* b_cat = (const float*)d_in[4];
    const float* W_f1  = (const float*)d_in[5];
    const float* b_f1  = (const float*)d_in[6];
    const float* W_f2  = (const float*)d_in[7];
    const float* b_f2  = (const float*)d_in[8];

    float* rowsum = (float*)d_ws;               // BB*NN
    float* rowsq  = rowsum + BB * NN;           // BB*NN
    float* outp   = (float*)d_out;

    pass_kernel<false><<<BB * BPB, 256, 0, stream>>>(
        x, W_out, b_out, W_cat, b_cat, W_f1, b_f1, W_f2, b_f2,
        rowsum, rowsq, outp);
    pass_kernel<true><<<BB * BPB, 256, 0, stream>>>(
        x, W_out, b_out, W_cat, b_cat, W_f1, b_f1, W_f2, b_f2,
        rowsum, rowsq, outp);
}

// Round 10
// 22.159 us; speedup vs baseline: 4.1937x; 4.1937x over previous
//
#include <hip/hip_runtime.h>
#include <math.h>

#define BB 16
#define NN 256
#define DD 32
#define RG 8               // rows per block
#define BPB (NN / RG)      // blocks per batch = 32

// Round-7 proven structure (22.4 us), restored verbatim after the round-9
// template/spill regression (WRITE_SIZE 4144->8704 KB = scratch traffic).
// Only change: expf -> __expf (v_exp_f32; round 8 validated accuracy).
//   K_pair : stage x[b] in LDS (swizzled), redundant per-thread u, per-block
//            v rows, pair compute, m -> d_out (pre-norm), rowsum/rowsq -> ws
//   K_final: redundant per-block batch stats (2KB, L2-hot) + in-place
//            normalize of d_out.
// LayerNorm algebra: with m2[i,j] = m[i,j] + rowmean_i,
//   sum(m2) = 2*sum(m);  sum(m2^2) = sum(m^2) + 3*N*sum_i(rowmean_i^2)
__attribute__((amdgpu_flat_work_group_size(256, 256), amdgpu_waves_per_eu(2, 2)))
__global__ void pair_kernel(
    const float* __restrict__ x,
    const float* __restrict__ W_out, const float* __restrict__ b_out,
    const float* __restrict__ W_cat, const float* __restrict__ b_cat,
    const float* __restrict__ W_f1,  const float* __restrict__ b_f1,
    const float* __restrict__ W_f2,  const float* __restrict__ b_f2,
    float* __restrict__ rowsum, float* __restrict__ rowsq,
    float* __restrict__ out)
{
    __shared__ float4 lx4[NN * 8];              // 32KB swizzled x[b]
    __shared__ float4 lv4[RG * 8];              // 512B rows' v
    __shared__ float  red0[RG][4], red1[RG][4];

    const int t  = threadIdx.x;
    const int b  = blockIdx.x >> 5;
    const int i0 = (blockIdx.x & 31) * RG;

    // ---- Phase 0: stage x[b], swizzled ----
    const float4* xb4 = (const float4*)(x + (size_t)b * NN * DD);
#pragma unroll
    for (int k = 0; k < 8; ++k) {
        int f = k * 256 + t;                    // 2048 float4s
        int n = f >> 3, c = f & 7;
        lx4[n * 8 + (c ^ (n & 7))] = xb4[f];
    }
    __syncthreads();

    // ---- Phase 1a: my column x_t -> regs ----
    float xj[DD];
#pragma unroll
    for (int c = 0; c < 8; ++c) {
        float4 xx = lx4[t * 8 + (c ^ (t & 7))];
        xj[4*c+0] = xx.x; xj[4*c+1] = xx.y; xj[4*c+2] = xx.z; xj[4*c+3] = xx.w;
    }

    // ---- Phase 1b: u_t = x_t @ W_top, 4 passes x 8 accumulators ----
    float u[DD];
#pragma unroll
    for (int p = 0; p < 4; ++p) {
        float acc[8];
#pragma unroll
        for (int j8 = 0; j8 < 8; ++j8) acc[j8] = 0.f;
#pragma unroll
        for (int k = 0; k < DD; ++k) {
            float xv = xj[k];
#pragma unroll
            for (int j8 = 0; j8 < 8; ++j8)
                acc[j8] += xv * W_out[k * DD + p * 8 + j8];   // uniform -> s_load
        }
#pragma unroll
        for (int j8 = 0; j8 < 8; ++j8) u[p * 8 + j8] = acc[j8];
    }

    // ---- Phase 1c: v for my block's 8 rows (thread = (row, dim)) ----
    {
        int r = t >> 5, d = t & 31;
        int i = i0 + r;
        const float* lxf = (const float*)lx4;
        float sv = 0.f;
#pragma unroll
        for (int k = 0; k < DD; ++k) {
            float xv = lxf[(i * 8 + ((k >> 2) ^ (i & 7))) * 4 + (k & 3)];
            sv += xv * W_out[(k + DD) * DD + d];              // coalesced vector
        }
        ((float*)lv4)[r * DD + d] = sv + b_out[d];
    }

    // small weights (wave-uniform -> scalar regs)
    float wcv[DD];
#pragma unroll
    for (int d = 0; d < DD; ++d) wcv[d] = W_cat[d];
    float f1a[8], f1b[8], fb1[8], f2w[8];
#pragma unroll
    for (int k = 0; k < 8; ++k) {
        f1a[k] = W_f1[k];        // W_f1[0,k]
        f1b[k] = W_f1[8 + k];    // W_f1[1,k]
        fb1[k] = b_f1[k];
        f2w[k] = W_f2[k];
    }
    const float bcat = b_cat[0], bf2 = b_f2[0];
    __syncthreads();

    // ---- Phase 2: pairs ----
    const int lane = t & 63, wv = t >> 6;
#pragma unroll
    for (int r = 0; r < RG; ++r) {
        int i = i0 + r;
        float e = 0.f, mp = 0.f;
#pragma unroll
        for (int q = 0; q < 8; ++q) {
            float4 vi = lv4[r * 8 + q];               // broadcast
            float4 xi = lx4[i * 8 + (q ^ (i & 7))];   // broadcast
            e += fmaxf(u[4*q+0] + vi.x, 0.f) * wcv[4*q+0];
            e += fmaxf(u[4*q+1] + vi.y, 0.f) * wcv[4*q+1];
            e += fmaxf(u[4*q+2] + vi.z, 0.f) * wcv[4*q+2];
            e += fmaxf(u[4*q+3] + vi.w, 0.f) * wcv[4*q+3];
            mp += xj[4*q+0]*xi.x + xj[4*q+1]*xi.y + xj[4*q+2]*xi.z + xj[4*q+3]*xi.w;
        }
        e = fmaxf(e + bcat, 0.f);
        float mlin = (t == i) ? 0.f : e;
        float s = bf2;
#pragma unroll
        for (int k = 0; k < 8; ++k)
            s += fmaxf(mlin * f1a[k] + mp * f1b[k] + fb1[k], 0.f) * f2w[k];
        float w = 1.f / (1.f + __expf(-s));
        float m = w * mlin + (1.f - w) * mp;

        out[((size_t)b * NN + i) * NN + t] = m;   // coalesced store (pre-norm)

        float sm = m, sq = m * m;                 // deterministic tree
#pragma unroll
        for (int off = 32; off; off >>= 1) {
            sm += __shfl_down(sm, off);
            sq += __shfl_down(sq, off);
        }
        if (lane == 0) { red0[r][wv] = sm; red1[r][wv] = sq; }
    }
    __syncthreads();
    if (t < RG) {
        rowsum[b * NN + i0 + t] = red0[t][0] + red0[t][1] + red0[t][2] + red0[t][3];
        rowsq [b * NN + i0 + t] = red1[t][0] + red1[t][1] + red1[t][2] + red1[t][3];
    }
}

// K_final: redundant per-block batch stats (2KB rowsum/rowsq, L2-hot) via
//   sum(m2) = 2*sum(m);  sum(m2^2) = sum(m^2) + 3*N*sum_i(rowmean_i^2)
// then in-place: out[b,i,j] = (out[b,i,j] + rowmean_i - mu) * rstd.
__global__ __launch_bounds__(256) void final_kernel(
    const float* __restrict__ rowsum, const float* __restrict__ rowsq,
    float* __restrict__ out)
{
    __shared__ float sred[12];
    __shared__ float stat[2];
    const int t  = threadIdx.x;
    const int b  = blockIdx.x >> 5;
    const int i0 = (blockIdx.x & 31) * RG;

    float rs = rowsum[b * NN + t];
    float rq = rowsq [b * NN + t];
    float rr = rs * (1.f / NN);
    float sM = rs, sQ = rq, sR = rr * rr;
#pragma unroll
    for (int off = 32; off; off >>= 1) {
        sM += __shfl_down(sM, off);
        sQ += __shfl_down(sQ, off);
        sR += __shfl_down(sR, off);
    }
    const int wave = t >> 6;
    if ((t & 63) == 0) { sred[wave] = sM; sred[4 + wave] = sQ; sred[8 + wave] = sR; }
    __syncthreads();
    if (t == 0) {
        float sumM  = sred[0] + sred[1] + sred[2] + sred[3];
        float sumQ  = sred[4] + sred[5] + sred[6] + sred[7];
        float sumR2 = sred[8] + sred[9] + sred[10] + sred[11];
        const float inv = 1.f / ((float)NN * (float)NN);
        float mu  = 2.f * sumM * inv;
        float ex2 = (sumQ + 3.f * (float)NN * sumR2) * inv;
        stat[0] = mu;
        stat[1] = rsqrtf(ex2 - mu * mu + 1e-5f);
    }
    __syncthreads();
    const float mu = stat[0], rstd = stat[1];
#pragma unroll
    for (int r = 0; r < RG; ++r) {
        int i = i0 + r;
        size_t base = ((size_t)b * NN + i) * NN;
        float ri = rowsum[b * NN + i] * (1.f / NN);   // uniform, L1-hot
        out[base + t] = (out[base + t] + ri - mu) * rstd;
    }
}

extern "C" void kernel_launch(void* const* d_in, const int* in_sizes, int n_in,
                              void* d_out, int out_size, void* d_ws, size_t ws_size,
                              hipStream_t stream)
{
    const float* x     = (const float*)d_in[0];
    const float* W_out = (const float*)d_in[1];
    const float* b_out = (const float*)d_in[2];
    const float* W_cat = (const float*)d_in[3];
    const float* b_cat = (const float*)d_in[4];
    const float* W_f1  = (const float*)d_in[5];
    const float* b_f1  = (const float*)d_in[6];
    const float* W_f2  = (const float*)d_in[7];
    const float* b_f2  = (const float*)d_in[8];

    float* rowsum = (float*)d_ws;               // BB*NN
    float* rowsq  = rowsum + BB * NN;           // BB*NN
    float* outp   = (float*)d_out;

    pair_kernel<<<BB * BPB, 256, 0, stream>>>(
        x, W_out, b_out, W_cat, b_cat, W_f1, b_f1, W_f2, b_f2,
        rowsum, rowsq, outp);
    final_kernel<<<BB * BPB, 256, 0, stream>>>(rowsum, rowsq, outp);
}